// Round 9
// baseline (133.026 us; speedup 1.0000x reference)
//
#include <hip/hip_runtime.h>
#include <math.h>

#define NOBS 9

typedef float f2 __attribute__((ext_vector_type(2)));
typedef unsigned u32x2 __attribute__((ext_vector_type(2)));

__device__ __forceinline__ float silu_f(float x) { return x / (1.f + expf(-x)); }
__device__ __forceinline__ f2 splat2(float x) { return (f2){x, x}; }
__device__ __forceinline__ f2 fma2(f2 a, f2 b, f2 c) { return __builtin_elementwise_fma(a, b, c); }

// ---------------- lane-exchange primitives (R3, verified) ----------------

template<int CTRL>
__device__ __forceinline__ float dpp_perm(float x) {
  return __int_as_float(__builtin_amdgcn_update_dpp(0, __float_as_int(x), CTRL, 0xF, 0xF, true));
}
template<int PAT>
__device__ __forceinline__ float ds_swz(float x) {
  return __int_as_float(__builtin_amdgcn_ds_swizzle(__float_as_int(x), PAT));
}
__device__ __forceinline__ float x4f(float x) { return ds_swz<0x101F>(x); }   // xor4

#if __has_builtin(__builtin_amdgcn_permlane32_swap)
#define PL32 1
__device__ __forceinline__ float x32(float x, bool sel) {
  u32x2 r = __builtin_amdgcn_permlane32_swap(__float_as_uint(x), __float_as_uint(x), false, false);
  return __uint_as_float(sel ? r.x : r.y);
}
__device__ __forceinline__ float sum32(float x) {
  u32x2 r = __builtin_amdgcn_permlane32_swap(__float_as_uint(x), __float_as_uint(x), false, false);
  return __uint_as_float(r.x) + __uint_as_float(r.y);
}
#else
#define PL32 0
__device__ __forceinline__ float x32(float x, bool sel) { return __shfl_xor(x, 32, 64); }
__device__ __forceinline__ float sum32(float x) { return x + __shfl_xor(x, 32, 64); }
#endif

#if __has_builtin(__builtin_amdgcn_permlane16_swap)
#define PL16 1
__device__ __forceinline__ float x16(float x, bool sel) {
  u32x2 r = __builtin_amdgcn_permlane16_swap(__float_as_uint(x), __float_as_uint(x), false, false);
  return __uint_as_float(sel ? r.x : r.y);
}
__device__ __forceinline__ float sum16(float x) {
  u32x2 r = __builtin_amdgcn_permlane16_swap(__float_as_uint(x), __float_as_uint(x), false, false);
  return __uint_as_float(r.x) + __uint_as_float(r.y);
}
#else
#define PL16 0
__device__ __forceinline__ float x16(float x, bool sel) { return ds_swz<0x401F>(x); }
__device__ __forceinline__ float sum16(float x) { return x + ds_swz<0x401F>(x); }
#endif

__device__ __forceinline__ float wave_sum(float x) {
  x += dpp_perm<0xB1>(x);
  x += dpp_perm<0x4E>(x);
  x += x4f(x);
  x += dpp_perm<0x128>(x);
  x = sum16(x);
  x = sum32(x);
  return x;
}

// ---------------- circuit gates (16 regs/lane, 1 wave per row; R3-verified) ----------------

template<int M>
__device__ __forceinline__ void ry_reg(float v[16], float c, float s) {
#pragma unroll
  for (int r = 0; r < 16; ++r) {
    if ((r & M) == 0) {
      float p0 = v[r], p1 = v[r | M];
      v[r]     = c * p0 - s * p1;
      v[r | M] = s * p0 + c * p1;
    }
  }
}

__device__ __forceinline__ void apply_rys(float v[16], int lane, bool sel32, bool sel16,
                                          const float* __restrict__ cc,
                                          const float* __restrict__ ss) {
  ry_reg<8>(v, cc[0], ss[0]);
  ry_reg<4>(v, cc[1], ss[1]);
  ry_reg<2>(v, cc[2], ss[2]);
  ry_reg<1>(v, cc[3], ss[3]);
  { float c = cc[4], s = ss[4], sp = (lane & 32) ? s : -s;
#pragma unroll
    for (int r = 0; r < 16; ++r) { float p = x32(v[r], sel32); v[r] = fmaf(c, v[r], sp * p); } }
  { float c = cc[5], s = ss[5], sp = (lane & 16) ? s : -s;
#pragma unroll
    for (int r = 0; r < 16; ++r) { float p = x16(v[r], sel16); v[r] = fmaf(c, v[r], sp * p); } }
  { float c = cc[6], s = ss[6], sp = (lane & 8) ? s : -s;
#pragma unroll
    for (int r = 0; r < 16; ++r) { float p = dpp_perm<0x128>(v[r]); v[r] = fmaf(c, v[r], sp * p); } }
  { float c = cc[7], s = ss[7], sp = (lane & 4) ? s : -s;
#pragma unroll
    for (int r = 0; r < 16; ++r) { float p = x4f(v[r]); v[r] = fmaf(c, v[r], sp * p); } }
  { float c = cc[8], s = ss[8], sp = (lane & 2) ? s : -s;
#pragma unroll
    for (int r = 0; r < 16; ++r) { float p = dpp_perm<0x4E>(v[r]); v[r] = fmaf(c, v[r], sp * p); } }
  { float c = cc[9], s = ss[9], sp = (lane & 1) ? s : -s;
#pragma unroll
    for (int r = 0; r < 16; ++r) { float p = dpp_perm<0xB1>(v[r]); v[r] = fmaf(c, v[r], sp * p); } }
}

__device__ __forceinline__ void cnot_ladder(float v[16], int lane, bool sel32, bool sel16) {
  float t;
  t=v[8];  v[8]=v[12];  v[12]=t;
  t=v[9];  v[9]=v[13];  v[13]=t;
  t=v[10]; v[10]=v[14]; v[14]=t;
  t=v[11]; v[11]=v[15]; v[15]=t;
  t=v[2];  v[2]=v[3];   v[3]=t;
  t=v[6];  v[6]=v[7];   v[7]=t;
  t=v[10]; v[10]=v[11]; v[11]=t;
  t=v[14]; v[14]=v[15]; v[15]=t;
  { bool c45 = (lane & 32);
#pragma unroll
    for (int r = 0; r < 16; ++r) { float p = x16(v[r], sel16); v[r] = c45 ? p : v[r]; } }
  { bool c67 = (lane & 8);
#pragma unroll
    for (int r = 0; r < 16; ++r) { float p = x4f(v[r]); v[r] = c67 ? p : v[r]; } }
  { bool c89 = (lane & 2);
#pragma unroll
    for (int r = 0; r < 16; ++r) { float p = dpp_perm<0xB1>(v[r]); v[r] = c89 ? p : v[r]; } }
  t=v[4];  v[4]=v[6];   v[6]=t;
  t=v[5];  v[5]=v[7];   v[7]=t;
  t=v[12]; v[12]=v[14]; v[14]=t;
  t=v[13]; v[13]=v[15]; v[15]=t;
#pragma unroll
  for (int r = 1; r < 16; r += 2) v[r] = x32(v[r], sel32);
  { bool c56 = (lane & 16);
#pragma unroll
    for (int r = 0; r < 16; ++r) { float p = dpp_perm<0x128>(v[r]); v[r] = c56 ? p : v[r]; } }
  { bool c78 = (lane & 4);
#pragma unroll
    for (int r = 0; r < 16; ++r) { float p = dpp_perm<0x4E>(v[r]); v[r] = c78 ? p : v[r]; } }
}

// ---------------- fused kernel: 8 rows / 512 threads / 1 block per CU ----------------
// LDS map (floats): [0,8192) stage (2x16KB dbuf; W2 20KB; circuit dump 8x1024)
//   [8192) xs2 f2[4][256] | [10240) hs2 f2[4][256] | [12288) hp2 f2[4][256]
//   [14336) cs[8][40] | [14656) sn[8][40] | [14976) vcs[64] | [15040) vsn[64] | [15104) os[8][9]

__global__ __launch_bounds__(512) void fused_kernel(
    const float* __restrict__ z, const float* __restrict__ t,
    const float* __restrict__ W1, const float* __restrict__ b1,
    const float* __restrict__ W2, const float* __restrict__ b2,
    const float* __restrict__ varp,
    const float* __restrict__ A_p, const float* __restrict__ D_p,
    const float* __restrict__ W3, const float* __restrict__ b3,
    const float* __restrict__ W4, const float* __restrict__ b4,
    float* __restrict__ out) {
  __shared__ __align__(16) float lds[15176];
  f2*    xs2 = (f2*)(lds + 8192);
  f2*    hs2 = (f2*)(lds + 10240);
  f2*    hp2 = (f2*)(lds + 12288);
  float* hsf = lds + 10240;
  float* cs_ = lds + 14336;
  float* sn_ = lds + 14656;
  float* vcs = lds + 14976;
  float* vsn = lds + 15040;
  float* osb = lds + 15104;

  const int tid  = threadIdx.x;          // 0..511
  const int b0   = blockIdx.x * 8;
  const int col  = tid & 255;
  const int half = tid >> 8;
  const int lane = tid & 63;
  const int wave = tid >> 6;             // 0..7 = row in circuit phase

  const float4* gW1 = (const float4*)W1;
  const float4* gW2 = (const float4*)W2;
  const float4* gW4 = (const float4*)W4;

  // ---- prologue: issue W1 tile-0 loads, fill xs2 + var cos/sin, write tile 0 ----
  float4 pre0 = gW1[tid], pre1 = gW1[512 + tid];
  __builtin_amdgcn_sched_barrier(0);

  if (tid < 60) {
    float s, c;
    sincosf(0.5f * varp[tid], &s, &c);
    vcs[tid] = c; vsn[tid] = s;
  }
  {
    int k = tid & 255, ph = tid >> 8;
#pragma unroll
    for (int q = 0; q < 2; ++q) {
      int rp = 2 * ph + q;               // row pair -> rows 2rp, 2rp+1
      if (k < 128) {
        xs2[rp * 256 + k] = (f2){z[(b0 + 2 * rp) * 128 + k], z[(b0 + 2 * rp + 1) * 128 + k]};
      } else {
        int i = k - 128, j = i & 63;
        float freq = expf(-9.2103403719761836f * (float)j * (1.f / 64.f));
        float a0 = t[b0 + 2 * rp] * freq, a1 = t[b0 + 2 * rp + 1] * freq;
        xs2[rp * 256 + k] = (i < 64) ? (f2){cosf(a0), cosf(a1)} : (f2){sinf(a0), sinf(a1)};
      }
    }
  }
  { float4* d = (float4*)lds; d[tid] = pre0; d[512 + tid] = pre1; }
  __syncthreads();

  // ---- phase 2: h = silu(x@W1+b1); 16 tiles x 16 k-rows, double-buffered LDS ----
  {
    f2 acc0 = splat2(b1[col]), acc1 = acc0;
    const int rp0 = 2 * half, rp1 = rp0 + 1;
#pragma unroll 1
    for (int tt = 0; tt < 16; ++tt) {
      if (tt < 15) {
        pre0 = gW1[(tt + 1) * 1024 + tid];
        pre1 = gW1[(tt + 1) * 1024 + 512 + tid];
        __builtin_amdgcn_sched_barrier(0);
      }
      const float* wt = lds + (tt & 1) * 4096;
#pragma unroll
      for (int kk = 0; kk < 16; ++kk) {
        float wv = wt[kk * 256 + col];
        int k = tt * 16 + kk;
        acc0 = fma2(xs2[rp0 * 256 + k], splat2(wv), acc0);
        acc1 = fma2(xs2[rp1 * 256 + k], splat2(wv), acc1);
      }
      if (tt < 15) {
        float4* d = (float4*)(lds + ((tt + 1) & 1) * 4096);
        d[tid] = pre0; d[512 + tid] = pre1;
      }
      __syncthreads();
    }
    hs2[rp0 * 256 + col] = (f2){silu_f(acc0.x), silu_f(acc0.y)};
    hs2[rp1 * 256 + col] = (f2){silu_f(acc1.x), silu_f(acc1.y)};
  }

  // ---- phase 3: ang = h@W2+b2 -> cos/sin(ang/2); W2 staged in 2 halves ----
  float p3acc = 0.f;
  const int p3r = tid / 40, p3c = tid - p3r * 40;   // valid when tid<320
  {
    // stage W2 rows 0..127 (1280 float4)
    float4 pa0 = gW2[tid], pa1 = gW2[512 + tid], pa2;
    if (tid < 256) pa2 = gW2[1024 + tid];
    __builtin_amdgcn_sched_barrier(0);
    {
      float4* d = (float4*)lds;
      d[tid] = pa0; d[512 + tid] = pa1; if (tid < 256) d[1024 + tid] = pa2;
    }
    __syncthreads();   // covers hs2 writes + W2A staging

    // issue W2 rows 128..255 loads, compute pass A
    float4 pb0 = gW2[1280 + tid], pb1 = gW2[1792 + tid], pb2;
    if (tid < 256) pb2 = gW2[2304 + tid];
    __builtin_amdgcn_sched_barrier(0);
    if (tid < 320) {
      float a = b2[p3c];
#pragma unroll 4
      for (int k = 0; k < 128; ++k)
        a = fmaf(hsf[(p3r >> 1) * 512 + 2 * k + (p3r & 1)], lds[k * 40 + p3c], a);
      p3acc = a;
    }
    __syncthreads();   // pass-A reads done before overwrite
    {
      float4* d = (float4*)lds;
      d[tid] = pb0; d[512 + tid] = pb1; if (tid < 256) d[1024 + tid] = pb2;
    }
    __syncthreads();
    if (tid < 320) {
      float a = p3acc;
#pragma unroll 4
      for (int k = 0; k < 128; ++k)
        a = fmaf(hsf[(p3r >> 1) * 512 + 2 * (128 + k) + (p3r & 1)], lds[k * 40 + p3c], a);
      float s, cv;
      sincosf(0.5f * a, &s, &cv);
      cs_[p3r * 40 + p3c] = cv;
      sn_[p3r * 40 + p3c] = s;
    }
  }
  __syncthreads();

  // ---- phase 4: circuit (wave = row); W4 tile-0 loads issued first (T14) ----
  float4 w4p0 = gW4[tid], w4p1 = gW4[512 + tid];
  __builtin_amdgcn_sched_barrier(0);
  {
    bool sel32 = true, sel16 = true;
#if PL32
    { u32x2 tt2 = __builtin_amdgcn_permlane32_swap((unsigned)lane, (unsigned)lane, false, false);
      sel32 = (tt2.x == (unsigned)(lane ^ 32)); }
#endif
#if PL16
    { u32x2 tt2 = __builtin_amdgcn_permlane16_swap((unsigned)lane, (unsigned)lane, false, false);
      sel16 = (tt2.x == (unsigned)(lane ^ 16)); }
#endif
    const float* cc = cs_ + wave * 40;
    const float* ss = sn_ + wave * 40;

    float base = 1.f;
    base *= (lane & 32) ? ss[4] : cc[4];
    base *= (lane & 16) ? ss[5] : cc[5];
    base *= (lane & 8)  ? ss[6] : cc[6];
    base *= (lane & 4)  ? ss[7] : cc[7];
    base *= (lane & 2)  ? ss[8] : cc[8];
    base *= (lane & 1)  ? ss[9] : cc[9];
    float v[16];
#pragma unroll
    for (int r = 0; r < 16; ++r) {
      float p = base;
      p *= (r & 8) ? ss[0] : cc[0];
      p *= (r & 4) ? ss[1] : cc[1];
      p *= (r & 2) ? ss[2] : cc[2];
      p *= (r & 1) ? ss[3] : cc[3];
      v[r] = p;
    }
    cnot_ladder(v, lane, sel32, sel16);
#pragma unroll 1
    for (int layer = 1; layer < 4; ++layer) {
      apply_rys(v, lane, sel32, sel16, cc + layer * 10, ss + layer * 10);
      if (layer < 3) cnot_ladder(v, lane, sel32, sel16);
    }
#pragma unroll 1
    for (int ly = 0; ly < 6; ++ly) {
      apply_rys(v, lane, sel32, sel16, vcs + ly * 10, vsn + ly * 10);
      cnot_ladder(v, lane, sel32, sel16);
    }

    // dump into stage region (dead between phase 3 and 5b)
    float* sw = lds + wave * 1024;
#pragma unroll
    for (int r = 0; r < 16; ++r) sw[r * 64 + lane] = v[r];

#pragma unroll 1
    for (int s = 0; s < NOBS; ++s) {
      const int r8 = 8 - s;
      const int stride = 1 << r8;
      float h10 = A_p[s*6+0], h20 = A_p[s*6+1], h21 = A_p[s*6+2];
      float h30 = A_p[s*6+3], h31 = A_p[s*6+4], h32 = A_p[s*6+5];
      float d0 = 2.f * D_p[s*4+1], d1 = 2.f * D_p[s*4+2], d2 = 2.f * D_p[s*4+3];
      float acc = 0.f;
#pragma unroll
      for (int k = 0; k < 4; ++k) {
        int p = lane + 64 * k;
        int a  = p >> r8;
        int rr = p & (stride - 1);
        int bse = (a << (r8 + 2)) + rr;
        float x0 = sw[bse];
        float x1 = sw[bse + stride];
        float x2 = sw[bse + 2 * stride];
        float x3 = sw[bse + 3 * stride];
        acc += d0 * x0 * x0 + d1 * x1 * x1 + d2 * x2 * x2
             + 2.f * (h10 * x1 * x0 + h20 * x2 * x0 + h21 * x2 * x1
                    + h30 * x3 * x0 + h31 * x3 * x1 + h32 * x3 * x2);
      }
      acc = wave_sum(acc);
      if (lane == 0) osb[wave * 9 + s] = acc;
    }
  }
  __syncthreads();   // os visible; dump consumed

  // ---- phase 5a: hh = silu(obs@W3+b3); also write W4 tile 0 ----
  { float4* d = (float4*)lds; d[tid] = w4p0; d[512 + tid] = w4p1; }
  {
    f2 a0 = splat2(b3[col]), a1 = a0;
#pragma unroll
    for (int s = 0; s < NOBS; ++s) {
      float wv = W3[s * 256 + col];
      a0 = fma2((f2){osb[(4 * half + 0) * 9 + s], osb[(4 * half + 1) * 9 + s]}, splat2(wv), a0);
      a1 = fma2((f2){osb[(4 * half + 2) * 9 + s], osb[(4 * half + 3) * 9 + s]}, splat2(wv), a1);
    }
    hp2[(2 * half) * 256 + col]     = (f2){silu_f(a0.x), silu_f(a0.y)};
    hp2[(2 * half + 1) * 256 + col] = (f2){silu_f(a1.x), silu_f(a1.y)};
  }
  __syncthreads();

  // ---- phase 5b: out = hh@W4 + b4; 8 tiles x 32 k-rows, double-buffered ----
  {
    const int c4 = tid & 127, rq = tid >> 7;   // rowpair rq -> rows 2rq, 2rq+1
    f2 acc = splat2(b4[c4]);
#pragma unroll 1
    for (int tt = 0; tt < 8; ++tt) {
      if (tt < 7) {
        w4p0 = gW4[(tt + 1) * 1024 + tid];
        w4p1 = gW4[(tt + 1) * 1024 + 512 + tid];
        __builtin_amdgcn_sched_barrier(0);
      }
      const float* wt = lds + (tt & 1) * 4096;
#pragma unroll
      for (int kk = 0; kk < 32; ++kk) {
        float wv = wt[kk * 128 + c4];
        int k = tt * 32 + kk;
        acc = fma2(hp2[rq * 256 + k], splat2(wv), acc);
      }
      if (tt < 7) {
        float4* d = (float4*)(lds + ((tt + 1) & 1) * 4096);
        d[tid] = w4p0; d[512 + tid] = w4p1;
      }
      __syncthreads();
    }
    out[(b0 + 2 * rq) * 128 + c4]     = acc.x;
    out[(b0 + 2 * rq + 1) * 128 + c4] = acc.y;
  }
}

// ---------------- launcher ----------------

extern "C" void kernel_launch(void* const* d_in, const int* in_sizes, int n_in,
                              void* d_out, int out_size, void* d_ws, size_t ws_size,
                              hipStream_t stream) {
  const float* z_t  = (const float*)d_in[0];
  const float* t    = (const float*)d_in[1];
  const float* W1   = (const float*)d_in[2];
  const float* b1   = (const float*)d_in[3];
  const float* W2   = (const float*)d_in[4];
  const float* b2   = (const float*)d_in[5];
  const float* varp = (const float*)d_in[6];
  const float* A_p  = (const float*)d_in[7];
  // d_in[8] = B_p: imaginary part of H -> contributes 0 for real psi
  const float* D_p  = (const float*)d_in[9];
  const float* W3   = (const float*)d_in[10];
  const float* b3   = (const float*)d_in[11];
  const float* W4   = (const float*)d_in[12];
  const float* b4   = (const float*)d_in[13];
  float* out = (float*)d_out;

  int B = in_sizes[1];  // t has one element per batch row

  fused_kernel<<<B / 8, 512, 0, stream>>>(z_t, t, W1, b1, W2, b2, varp,
                                          A_p, D_p, W3, b3, W4, b4, out);
}

// Round 10
// 132.050 us; speedup vs baseline: 1.0074x; 1.0074x over previous
//
#include <hip/hip_runtime.h>
#include <math.h>
#include <stdint.h>

#define NOBS 9

typedef float f2 __attribute__((ext_vector_type(2)));

__device__ __forceinline__ float silu_f(float x) { return x / (1.f + expf(-x)); }
__device__ __forceinline__ f2 splat2(float x) { return (f2){x, x}; }
__device__ __forceinline__ f2 fma2(f2 a, f2 b, f2 c) { return __builtin_elementwise_fma(a, b, c); }

// ---------------- async global->LDS DMA ----------------
typedef const __attribute__((address_space(1))) uint32_t* gas_t;
typedef __attribute__((address_space(3))) uint32_t* las_t;
__device__ __forceinline__ void gl4(const float* g, float* l) {
  __builtin_amdgcn_global_load_lds((gas_t)g, (las_t)l, 4, 0, 0);   // 64 lanes x 4B -> 256B
}
__device__ __forceinline__ void gl16(const float* g, float* l) {
  __builtin_amdgcn_global_load_lds((gas_t)g, (las_t)l, 16, 0, 0);  // 64 lanes x 16B -> 1KB
}
#define WAITVM(N) do { asm volatile("s_waitcnt vmcnt(" #N ")" ::: "memory"); \
                       __builtin_amdgcn_sched_barrier(0); } while (0)

// ---------------- lane-exchange primitives (R8-verified) ----------------
template<int CTRL>
__device__ __forceinline__ float dpp_perm(float x) {
  return __int_as_float(__builtin_amdgcn_update_dpp(0, __float_as_int(x), CTRL, 0xF, 0xF, true));
}
template<int PAT>
__device__ __forceinline__ float ds_swz(float x) {
  return __int_as_float(__builtin_amdgcn_ds_swizzle(__float_as_int(x), PAT));
}
__device__ __forceinline__ float x4f(float x) { return ds_swz<0x101F>(x); }   // xor4

__device__ __forceinline__ float wave_sum(float x) {
  x += dpp_perm<0xB1>(x);
  x += dpp_perm<0x4E>(x);
  x += x4f(x);
  x += dpp_perm<0x128>(x);
  x += ds_swz<0x401F>(x);
  x += __shfl_xor(x, 32, 64);
  return x;
}

// ---------------- circuit gates (16 regs/lane, 1 wave/row; R8-verified) ----------------
template<int M>
__device__ __forceinline__ void ry_reg(float v[16], float c, float s) {
#pragma unroll
  for (int r = 0; r < 16; ++r) {
    if ((r & M) == 0) {
      float p0 = v[r], p1 = v[r | M];
      v[r]     = c * p0 - s * p1;
      v[r | M] = s * p0 + c * p1;
    }
  }
}

__device__ __forceinline__ void apply_rys(float v[16], int lane,
                                          const float* __restrict__ cc,
                                          const float* __restrict__ ss) {
  ry_reg<8>(v, cc[0], ss[0]);
  ry_reg<4>(v, cc[1], ss[1]);
  ry_reg<2>(v, cc[2], ss[2]);
  ry_reg<1>(v, cc[3], ss[3]);
  { float c = cc[4], s = ss[4], sp = (lane & 32) ? s : -s;
#pragma unroll
    for (int r = 0; r < 16; ++r) { float p = __shfl_xor(v[r], 32, 64); v[r] = fmaf(c, v[r], sp * p); } }
  { float c = cc[5], s = ss[5], sp = (lane & 16) ? s : -s;
#pragma unroll
    for (int r = 0; r < 16; ++r) { float p = __shfl_xor(v[r], 16, 64); v[r] = fmaf(c, v[r], sp * p); } }
  { float c = cc[6], s = ss[6], sp = (lane & 8) ? s : -s;
#pragma unroll
    for (int r = 0; r < 16; ++r) { float p = dpp_perm<0x128>(v[r]); v[r] = fmaf(c, v[r], sp * p); } }
  { float c = cc[7], s = ss[7], sp = (lane & 4) ? s : -s;
#pragma unroll
    for (int r = 0; r < 16; ++r) { float p = x4f(v[r]); v[r] = fmaf(c, v[r], sp * p); } }
  { float c = cc[8], s = ss[8], sp = (lane & 2) ? s : -s;
#pragma unroll
    for (int r = 0; r < 16; ++r) { float p = dpp_perm<0x4E>(v[r]); v[r] = fmaf(c, v[r], sp * p); } }
  { float c = cc[9], s = ss[9], sp = (lane & 1) ? s : -s;
#pragma unroll
    for (int r = 0; r < 16; ++r) { float p = dpp_perm<0xB1>(v[r]); v[r] = fmaf(c, v[r], sp * p); } }
}

__device__ __forceinline__ void cnot_ladder(float v[16], int lane) {
  float t;
  t=v[8];  v[8]=v[12];  v[12]=t;
  t=v[9];  v[9]=v[13];  v[13]=t;
  t=v[10]; v[10]=v[14]; v[14]=t;
  t=v[11]; v[11]=v[15]; v[15]=t;
  t=v[2];  v[2]=v[3];   v[3]=t;
  t=v[6];  v[6]=v[7];   v[7]=t;
  t=v[10]; v[10]=v[11]; v[11]=t;
  t=v[14]; v[14]=v[15]; v[15]=t;
  int se = lane ^ ((lane & 42) >> 1);
#pragma unroll
  for (int r = 0; r < 16; ++r) v[r] = __shfl(v[r], se, 64);
  t=v[4];  v[4]=v[6];   v[6]=t;
  t=v[5];  v[5]=v[7];   v[7]=t;
  t=v[12]; v[12]=v[14]; v[14]=t;
  t=v[13]; v[13]=v[15]; v[15]=t;
  int so  = lane ^ ((lane & 20) >> 1);
  int so1 = so ^ 32;
#pragma unroll
  for (int r = 0; r < 16; ++r) v[r] = __shfl(v[r], (r & 1) ? so1 : so, 64);
}

// ---------------- LDS map (float offsets) ----------------
#define RING 0        // 4 waves x 24 slots x 64 = 6144
#define XS   6144     // float4[256] = 1024
#define HS   7168     // [4][256] = 1024
#define W2O  8192     // 10240 (W2 stage); overlays: DUMP @W2O (4096), W3 @12288 (2304),
#define W3O  12288    //   HP4 @14592 (1024), PART @15616 (512)
#define HP4O 14592
#define PARTO 15616
#define CS   18432    // [4][40]
#define SN   18592
#define VCS  18752
#define VSN  18816
#define OSB  18880    // [4][9]
#define LDSF 18944

// ---------------- fused kernel: 4 rows / 256 threads / grid B/4 ----------------

__global__ __launch_bounds__(256, 2) void fused_kernel(
    const float* __restrict__ z, const float* __restrict__ t,
    const float* __restrict__ W1, const float* __restrict__ b1,
    const float* __restrict__ W2, const float* __restrict__ b2,
    const float* __restrict__ varp,
    const float* __restrict__ A_p, const float* __restrict__ D_p,
    const float* __restrict__ W3, const float* __restrict__ b3,
    const float* __restrict__ W4, const float* __restrict__ b4,
    float* __restrict__ out) {
  __shared__ __align__(16) float lds[LDSF];
  float4* xs4 = (float4*)(lds + XS);
  float4* hp4 = (float4*)(lds + HP4O);
  float4* part4 = (float4*)(lds + PARTO);

  const int tid  = threadIdx.x;
  const int b0   = blockIdx.x * 4;
  const int w    = tid >> 6;
  const int lane = tid & 63;
  const int c0   = w * 64;
  const int ringw = w * 1536;      // 24 slots x 64 floats per wave

  // ---- phase 1: x = [z, cos(t f), sin(t f)] packed as float4 rows ----
  if (tid < 128) {
    int k = tid;
    xs4[k] = (float4){z[(b0 + 0) * 128 + k], z[(b0 + 1) * 128 + k],
                      z[(b0 + 2) * 128 + k], z[(b0 + 3) * 128 + k]};
  } else {
    int i = tid - 128, j = i & 63;
    float freq = expf(-9.2103403719761836f * (float)j * (1.f / 64.f));
    float a0 = t[b0] * freq, a1 = t[b0 + 1] * freq, a2 = t[b0 + 2] * freq, a3 = t[b0 + 3] * freq;
    float4 xv = (i < 64) ? (float4){cosf(a0), cosf(a1), cosf(a2), cosf(a3)}
                         : (float4){sinf(a0), sinf(a1), sinf(a2), sinf(a3)};
    xs4[128 + i] = xv;
  }
  if (tid < 60) {
    float s, c;
    sincosf(0.5f * varp[tid], &s, &c);
    lds[VCS + tid] = c; lds[VSN + tid] = s;
  }
  __syncthreads();

  // ---- phase 2: h = silu(x@W1+b1); per-wave async ring, no barriers in loop ----
  {
    // stage W2 (consumed in phase 3) -- issued first, lands during phase 2
#pragma unroll
    for (int q = 0; q < 10; ++q) {
      int i = w * 10 + q;
      gl16(W2 + i * 256 + lane * 4, lds + W2O + i * 256);
    }
    // W1 ring prologue: blocks 0,1 (16 k-rows)
#pragma unroll
    for (int k = 0; k < 16; ++k)
      gl4(W1 + k * 256 + c0 + lane, lds + ringw + k * 64);

    f2 a01 = splat2(b1[c0 + lane]), a23 = a01;
    int sbi = 2, sbp = 0;
#pragma unroll 1
    for (int kb = 0; kb < 30; ++kb) {
      int kbase = (kb + 2) * 8;
#pragma unroll
      for (int j = 0; j < 8; ++j)
        gl4(W1 + (kbase + j) * 256 + c0 + lane, lds + ringw + (sbi * 8 + j) * 64);
      WAITVM(16);
#pragma unroll
      for (int j = 0; j < 8; ++j) {
        float wv = lds[ringw + (sbp * 8 + j) * 64 + lane];
        float4 x = xs4[kb * 8 + j];
        a01 = fma2((f2){x.x, x.y}, splat2(wv), a01);
        a23 = fma2((f2){x.z, x.w}, splat2(wv), a23);
      }
      sbi = (sbi == 2) ? 0 : sbi + 1;
      sbp = (sbp == 2) ? 0 : sbp + 1;
    }
    WAITVM(8);
#pragma unroll
    for (int j = 0; j < 8; ++j) {
      float wv = lds[ringw + (sbp * 8 + j) * 64 + lane];
      float4 x = xs4[240 + j];
      a01 = fma2((f2){x.x, x.y}, splat2(wv), a01);
      a23 = fma2((f2){x.z, x.w}, splat2(wv), a23);
    }
    sbp = (sbp == 2) ? 0 : sbp + 1;
    WAITVM(0);
#pragma unroll
    for (int j = 0; j < 8; ++j) {
      float wv = lds[ringw + (sbp * 8 + j) * 64 + lane];
      float4 x = xs4[248 + j];
      a01 = fma2((f2){x.x, x.y}, splat2(wv), a01);
      a23 = fma2((f2){x.z, x.w}, splat2(wv), a23);
    }
    int c = c0 + lane;
    lds[HS + 0 * 256 + c] = silu_f(a01.x);
    lds[HS + 1 * 256 + c] = silu_f(a01.y);
    lds[HS + 2 * 256 + c] = silu_f(a23.x);
    lds[HS + 3 * 256 + c] = silu_f(a23.y);
  }
  __syncthreads();   // hs + W2 ready (barrier drains vmcnt)

  // ---- phase 3: ang = h@W2+b2 -> cos/sin(ang/2); all-LDS ----
  if (tid < 160) {
    int r = tid / 40, c = tid - r * 40;
    float acc = b2[c];
#pragma unroll 8
    for (int k = 0; k < 256; ++k)
      acc = fmaf(lds[HS + r * 256 + k], lds[W2O + k * 40 + c], acc);
    float s, cv;
    sincosf(0.5f * acc, &s, &cv);
    lds[CS + r * 40 + c] = cv;
    lds[SN + r * 40 + c] = s;
  }
  __syncthreads();

  // ---- phase 4: circuit (wave = row); stage W3 async during circuit ----
  for (int i = w; i < 9; i += 4)
    gl16(W3 + i * 256 + lane * 4, lds + W3O + i * 256);
  {
    const float* cc = lds + CS + w * 40;
    const float* ss = lds + SN + w * 40;
    const float* vcs = lds + VCS;
    const float* vsn = lds + VSN;

    float base = 1.f;
    base *= (lane & 32) ? ss[4] : cc[4];
    base *= (lane & 16) ? ss[5] : cc[5];
    base *= (lane & 8)  ? ss[6] : cc[6];
    base *= (lane & 4)  ? ss[7] : cc[7];
    base *= (lane & 2)  ? ss[8] : cc[8];
    base *= (lane & 1)  ? ss[9] : cc[9];
    float v[16];
#pragma unroll
    for (int r = 0; r < 16; ++r) {
      float p = base;
      p *= (r & 8) ? ss[0] : cc[0];
      p *= (r & 4) ? ss[1] : cc[1];
      p *= (r & 2) ? ss[2] : cc[2];
      p *= (r & 1) ? ss[3] : cc[3];
      v[r] = p;
    }
    cnot_ladder(v, lane);
#pragma unroll 1
    for (int layer = 1; layer < 4; ++layer) {
      apply_rys(v, lane, cc + layer * 10, ss + layer * 10);
      if (layer < 3) cnot_ladder(v, lane);
    }
#pragma unroll 1
    for (int ly = 0; ly < 6; ++ly) {
      apply_rys(v, lane, vcs + ly * 10, vsn + ly * 10);
      cnot_ladder(v, lane);
    }

    float* sw = lds + W2O + w * 1024;   // dump overlays dead W2 region
#pragma unroll
    for (int r = 0; r < 16; ++r) sw[r * 64 + lane] = v[r];

#pragma unroll 1
    for (int s = 0; s < NOBS; ++s) {
      const int r8 = 8 - s;
      const int stride = 1 << r8;
      float h10 = A_p[s*6+0], h20 = A_p[s*6+1], h21 = A_p[s*6+2];
      float h30 = A_p[s*6+3], h31 = A_p[s*6+4], h32 = A_p[s*6+5];
      float d0 = 2.f * D_p[s*4+1], d1 = 2.f * D_p[s*4+2], d2 = 2.f * D_p[s*4+3];
      float acc = 0.f;
#pragma unroll
      for (int k = 0; k < 4; ++k) {
        int p = lane + 64 * k;
        int a  = p >> r8;
        int rr = p & (stride - 1);
        int bse = (a << (r8 + 2)) + rr;
        float x0 = sw[bse];
        float x1 = sw[bse + stride];
        float x2 = sw[bse + 2 * stride];
        float x3 = sw[bse + 3 * stride];
        acc += d0 * x0 * x0 + d1 * x1 * x1 + d2 * x2 * x2
             + 2.f * (h10 * x1 * x0 + h20 * x2 * x0 + h21 * x2 * x1
                    + h30 * x3 * x0 + h31 * x3 * x1 + h32 * x3 * x2);
      }
      acc = wave_sum(acc);
      if (lane == 0) lds[OSB + w * 9 + s] = acc;
    }
  }
  __syncthreads();   // osb visible; W3 landed (drain)

  // ---- phase 5a: hh = silu(obs@W3+b3) ----
  {
    int col = tid;
    f2 q01 = splat2(b3[col]), q23 = q01;
#pragma unroll
    for (int s = 0; s < NOBS; ++s) {
      float wv = lds[W3O + s * 256 + col];
      q01 = fma2((f2){lds[OSB + 0 * 9 + s], lds[OSB + 1 * 9 + s]}, splat2(wv), q01);
      q23 = fma2((f2){lds[OSB + 2 * 9 + s], lds[OSB + 3 * 9 + s]}, splat2(wv), q23);
    }
    hp4[col] = (float4){silu_f(q01.x), silu_f(q01.y), silu_f(q23.x), silu_f(q23.y)};
  }
  __syncthreads();

  // ---- phase 5b: out = hh@W4 + b4; per-wave ring (col-half x k-half) ----
  {
    const int c0b = (w & 1) * 64;
    const int kh  = (w >> 1) * 128;
#pragma unroll
    for (int kl = 0; kl < 16; ++kl)
      gl4(W4 + (kh + kl) * 128 + c0b + lane, lds + ringw + kl * 64);

    f2 a01 = splat2(0.f), a23 = splat2(0.f);
    int sbi = 2, sbp = 0;
#pragma unroll 1
    for (int kb = 0; kb < 14; ++kb) {
      int kbase = (kb + 2) * 8;
#pragma unroll
      for (int j = 0; j < 8; ++j)
        gl4(W4 + (kh + kbase + j) * 128 + c0b + lane, lds + ringw + (sbi * 8 + j) * 64);
      WAITVM(16);
#pragma unroll
      for (int j = 0; j < 8; ++j) {
        float wv = lds[ringw + (sbp * 8 + j) * 64 + lane];
        float4 h = hp4[kh + kb * 8 + j];
        a01 = fma2((f2){h.x, h.y}, splat2(wv), a01);
        a23 = fma2((f2){h.z, h.w}, splat2(wv), a23);
      }
      sbi = (sbi == 2) ? 0 : sbi + 1;
      sbp = (sbp == 2) ? 0 : sbp + 1;
    }
    WAITVM(8);
#pragma unroll
    for (int j = 0; j < 8; ++j) {
      float wv = lds[ringw + (sbp * 8 + j) * 64 + lane];
      float4 h = hp4[kh + 112 + j];
      a01 = fma2((f2){h.x, h.y}, splat2(wv), a01);
      a23 = fma2((f2){h.z, h.w}, splat2(wv), a23);
    }
    sbp = (sbp == 2) ? 0 : sbp + 1;
    WAITVM(0);
#pragma unroll
    for (int j = 0; j < 8; ++j) {
      float wv = lds[ringw + (sbp * 8 + j) * 64 + lane];
      float4 h = hp4[kh + 120 + j];
      a01 = fma2((f2){h.x, h.y}, splat2(wv), a01);
      a23 = fma2((f2){h.z, h.w}, splat2(wv), a23);
    }
    if (w >= 2) part4[(w - 2) * 64 + lane] = (float4){a01.x, a01.y, a23.x, a23.y};
    __syncthreads();
    if (w < 2) {
      float4 p = part4[w * 64 + lane];
      int c = c0b + lane;
      float bb = b4[c];
      out[(b0 + 0) * 128 + c] = a01.x + p.x + bb;
      out[(b0 + 1) * 128 + c] = a01.y + p.y + bb;
      out[(b0 + 2) * 128 + c] = a23.x + p.z + bb;
      out[(b0 + 3) * 128 + c] = a23.y + p.w + bb;
    }
  }
}

// ---------------- launcher ----------------

extern "C" void kernel_launch(void* const* d_in, const int* in_sizes, int n_in,
                              void* d_out, int out_size, void* d_ws, size_t ws_size,
                              hipStream_t stream) {
  const float* z_t  = (const float*)d_in[0];
  const float* t    = (const float*)d_in[1];
  const float* W1   = (const float*)d_in[2];
  const float* b1   = (const float*)d_in[3];
  const float* W2   = (const float*)d_in[4];
  const float* b2   = (const float*)d_in[5];
  const float* varp = (const float*)d_in[6];
  const float* A_p  = (const float*)d_in[7];
  // d_in[8] = B_p: imaginary part of H -> contributes 0 for real psi
  const float* D_p  = (const float*)d_in[9];
  const float* W3   = (const float*)d_in[10];
  const float* b3   = (const float*)d_in[11];
  const float* W4   = (const float*)d_in[12];
  const float* b4   = (const float*)d_in[13];
  float* out = (float*)d_out;

  int B = in_sizes[1];  // t has one element per batch row

  fused_kernel<<<B / 4, 256, 0, stream>>>(z_t, t, W1, b1, W2, b2, varp,
                                          A_p, D_p, W3, b3, W4, b4, out);
}